// Round 5
// baseline (15832.681 us; speedup 1.0000x reference)
//
#include <hip/hip_runtime.h>

// ----------------------------------------------------------------------------
// 2-layer LayerNorm-LSTM, SEQ=1024, B=64, IN=256, H=512.
// 64 persistent WGs: bid 0..31 = layer-0 team, 32..63 = layer-1 team.
// Each WG owns 16 hidden columns (all 4 gates), weights fully LDS-resident
// (96/128 KB), fused matmul (bf16 MFMA) + elementwise + LN, cell state in
// registers. Cross-WG: h via sc0+sc1 loads + u32 flags (round-4-proven);
// LN stats via SELF-VALIDATING 8B atomics — parity of step encoded in
// signbit(sum-of-squares), so the stats hop needs no flag, no producer
// vmcnt ack, and settles in ONE round trip (the poll IS the data read).
// ----------------------------------------------------------------------------

typedef short  s16x8 __attribute__((ext_vector_type(8)));
typedef float  f32x4 __attribute__((ext_vector_type(4)));
typedef float  f32x2 __attribute__((ext_vector_type(2)));
typedef unsigned short u16;
typedef unsigned int   u32;
typedef unsigned long long u64;

constexpr int kSeq = 1024;

// ws layout (bytes)
constexpr size_t OF_FLAGS = 0;            // u32[64]: HFA[32] HF1[32]
constexpr size_t OF_STAT0 = 1024;         // [64 rows][32 prod] float2 = 16384
constexpr size_t OF_STAT1 = 17408;        // 16384
constexpr size_t OF_HA    = 33792;        // [2 parity][64][512] u16 = 131072
constexpr size_t OF_HB    = 164864;       // 131072
constexpr size_t OF_W0S   = 295936;       // 32*24*4*64*8 u16 = 3145728
constexpr size_t OF_W1S   = 3441664;      // 32*32*4*64*8 u16 = 4194304
constexpr size_t OF_XBF   = 7635968;      // 1024*64*256 u16 = 33554432
constexpr size_t WS_NEED  = OF_XBF + 33554432;

constexpr size_t OUT_HFIN = (size_t)kSeq * 64 * 512;
constexpr size_t OUT_CFIN = OUT_HFIN + 2 * 64 * 512;

__device__ __forceinline__ u16 f2bf(float f) {
  u32 u = __float_as_uint(f);
  return (u16)((u + 0x7fffu + ((u >> 16) & 1u)) >> 16);  // RNE; finite inputs
}

// ---------------- LLC-coherent (sc0 sc1) access helpers ---------------------
__device__ __forceinline__ void ldg16_coh(s16x8& d, const void* p) {
  asm volatile("global_load_dwordx4 %0, %1, off sc0 sc1" : "=v"(d) : "v"(p) : "memory");
}
__device__ __forceinline__ void ldg8f_coh(f32x2& d, const void* p) {
  asm volatile("global_load_dwordx2 %0, %1, off sc0 sc1" : "=v"(d) : "v"(p) : "memory");
}
__device__ __forceinline__ void stg8_coh(float* p, float a, float b) {
  f32x2 t; t[0] = a; t[1] = b;
  asm volatile("global_store_dwordx2 %0, %1, off sc0 sc1" :: "v"(p), "v"(t) : "memory");
}
__device__ __forceinline__ void stg2_coh(u16* p, u32 v) {
  asm volatile("global_store_short %0, %1, off sc0 sc1" :: "v"(p), "v"(v) : "memory");
}
__device__ __forceinline__ void vm_wait() {
  asm volatile("s_waitcnt vmcnt(0)" ::: "memory");
  __builtin_amdgcn_sched_barrier(0);     // rule 18: nothing crosses the wait
}
// Spin until all 32 flags >= tgt (all 64 lanes read flags[lane&31]).
__device__ __forceinline__ void waitge(u32* f, u32 tgt) {
  const int l = threadIdx.x & 31;
  while (true) {
    u32 v = __hip_atomic_load(&f[l], __ATOMIC_RELAXED, __HIP_MEMORY_SCOPE_AGENT);
    if (__all((int)(v >= tgt))) break;
    __builtin_amdgcn_s_sleep(2);
  }
}

// ---------------------------------------------------------------- conversions
__global__ void conv_x_k(const float* __restrict__ x, u16* __restrict__ xd, size_t n) {
  size_t i = (size_t)blockIdx.x * blockDim.x + threadIdx.x;
  size_t st = (size_t)gridDim.x * blockDim.x;
  for (; i < n; i += st) xd[i] = f2bf(x[i]);
}

// W [2048][Kdim] -> [ns(32)][kst(KST)][nt(4)][lane(64)][e(8)]
// n_orig = nt*512 + ns*16 + (lane&15); k = kst*32 + (lane>>4)*8 + e
__global__ void conv_w_k(const float* __restrict__ W, u16* __restrict__ Wd,
                         int KST, int Kdim) {
  int i = blockIdx.x * blockDim.x + threadIdx.x;
  if (i >= 32 * KST * 2048) return;
  int e = i & 7, lane = (i >> 3) & 63, nt = (i >> 9) & 3;
  int r = i >> 11;
  int kst = r % KST, ns = r / KST;
  int n_orig = nt * 512 + ns * 16 + (lane & 15);
  int k = kst * 32 + ((lane >> 4) << 3) + e;
  Wd[i] = f2bf(W[(size_t)n_orig * Kdim + k]);
}

__global__ void init_k(char* ws, const float* __restrict__ h0) {
  int i = blockIdx.x * blockDim.x + threadIdx.x;   // 0..32767
  u32* f = (u32*)ws;
  if (i < 64) f[i] = 0u;
  if (i < 4096) {       // stats entries -> (s=0, q=-0.0): signbit 1 != (t=0)&1
    ((u64*)(ws + OF_STAT0))[i] = 0x8000000000000000ull;
    ((u64*)(ws + OF_STAT1))[i] = 0x8000000000000000ull;
  }
  // parity-1 buffers <- initial hidden states
  ((u16*)(ws + OF_HA))[32768 + i] = f2bf(h0[i]);
  ((u16*)(ws + OF_HB))[32768 + i] = f2bf(h0[32768 + i]);
}

// ---------------------------------------------------------------- team loop
template <int ROLE>
__device__ __forceinline__ void team_loop(
    int ns, char* smem,
    const u16* __restrict__ xbf, const u16* __restrict__ wsw,
    u16* hA, u16* hB, float* statT, u32* flags,
    const float* __restrict__ bias, const float* __restrict__ gam_,
    const float* __restrict__ bet_, const float* __restrict__ c0in,
    float* __restrict__ out)
{
  constexpr int KST = ROLE ? 32 : 24;     // K/32
  const int tid = threadIdx.x;
  const int lane = tid & 63, wid = tid >> 6;
  const int arow = wid * 16 + (lane & 15);        // batch row of A-frag
  const int acol = (lane >> 4) << 3;              // K offset within 32
  const int jl = tid & 15, rg = tid >> 4;         // EW col-in-16, row-group
  const int jg = ns * 16 + jl;                    // owned hidden column

  u32* HFA = flags;
  u32* HF1 = flags + 32;
  u32* HF  = ROLE ? HF1 : HFA;

  s16x8* wl    = (s16x8*)smem;                    // KST*4 KB weights
  float* gates = (float*)(smem + (size_t)KST * 4096);   // [4][64][17] f32
  float* mus   = (float*)(smem + (size_t)KST * 4096 + 17408); // [64][2]

  // weights fully into LDS
  const s16x8* wsrc = (const s16x8*)wsw + (size_t)ns * KST * 256;
  for (int i = tid; i < KST * 256; i += 256) wl[i] = wsrc[i];

  const float bi = bias[jg], bf_ = bias[512 + jg], bo = bias[1024 + jg], bc = bias[1536 + jg];
  const float gm = gam_[jg], bt = bet_[jg];
  float cst[4];
  #pragma unroll
  for (int k = 0; k < 4; ++k)
    cst[k] = c0in[(size_t)(ROLE * 64 + rg * 4 + k) * 512 + jg];
  __syncthreads();

  for (int t = 0; t < kSeq; ++t) {
    f32x4 acc[4];
    #pragma unroll
    for (int nt = 0; nt < 4; ++nt) acc[nt] = (f32x4){0.f, 0.f, 0.f, 0.f};

    // ------------- matmul: gates[64b][64 gatecols] = act(t) @ W^T
    if (ROLE == 0) {
      s16x8 xp[8];
      const u16* xr = xbf + ((size_t)t * 64 + arow) * 256 + acol;
      #pragma unroll
      for (int kk = 0; kk < 8; ++kk) xp[kk] = *(const s16x8*)(xr + kk * 32);
      if (wid == 0)      { if (t > 0)  waitge(HFA, (u32)t); }        // h(t-1)
      else if (wid == 1) { if (t >= 2) waitge(HF1, (u32)(t - 1)); }  // hA overwrite bp
      __syncthreads();
      s16x8 a[16];
      const u16* hr = hA + (size_t)((t + 1) & 1) * 32768 + (size_t)arow * 512 + acol;
      #pragma unroll
      for (int kk = 0; kk < 16; ++kk) ldg16_coh(a[kk], hr + kk * 32);
      #pragma unroll
      for (int kk = 0; kk < 8; ++kk)
        #pragma unroll
        for (int nt = 0; nt < 4; ++nt)
          acc[nt] = __builtin_amdgcn_mfma_f32_16x16x32_bf16(xp[kk], wl[(kk * 4 + nt) * 64 + lane], acc[nt], 0, 0, 0);
      vm_wait();
      #pragma unroll
      for (int kk = 0; kk < 16; ++kk)
        #pragma unroll
        for (int nt = 0; nt < 4; ++nt)
          acc[nt] = __builtin_amdgcn_mfma_f32_16x16x32_bf16(a[kk], wl[((8 + kk) * 4 + nt) * 64 + lane], acc[nt], 0, 0, 0);
    } else {
      if (wid == 0) { if (t > 0) waitge(HF1, (u32)t); }              // own hB(t-1)
      __syncthreads();
      s16x8 a[16];
      const u16* hbr = hB + (size_t)((t + 1) & 1) * 32768 + (size_t)arow * 512 + acol;
      #pragma unroll
      for (int kk = 0; kk < 16; ++kk) ldg16_coh(a[kk], hbr + kk * 32);
      vm_wait();
      #pragma unroll
      for (int kk = 0; kk < 16; ++kk)
        #pragma unroll
        for (int nt = 0; nt < 4; ++nt)
          acc[nt] = __builtin_amdgcn_mfma_f32_16x16x32_bf16(a[kk], wl[((16 + kk) * 4 + nt) * 64 + lane], acc[nt], 0, 0, 0);
      if (wid == 0) waitge(HFA, (u32)(t + 1));                        // fresh hA(t)
      __syncthreads();
      const u16* har = hA + (size_t)(t & 1) * 32768 + (size_t)arow * 512 + acol;
      #pragma unroll
      for (int kk = 0; kk < 16; ++kk) ldg16_coh(a[kk], har + kk * 32);
      vm_wait();
      #pragma unroll
      for (int kk = 0; kk < 16; ++kk)
        #pragma unroll
        for (int nt = 0; nt < 4; ++nt)
          acc[nt] = __builtin_amdgcn_mfma_f32_16x16x32_bf16(a[kk], wl[(kk * 4 + nt) * 64 + lane], acc[nt], 0, 0, 0);
    }

    // D layout: col = lane&15, row = (lane>>4)*4 + r  [m89]; gate = nt
    #pragma unroll
    for (int nt = 0; nt < 4; ++nt) {
      const int brow = wid * 16 + ((lane >> 4) << 2);
      #pragma unroll
      for (int r = 0; r < 4; ++r)
        gates[(nt * 64 + brow + r) * 17 + (lane & 15)] = acc[nt][r];
    }
    __syncthreads();

    // ------------- elementwise (4 cells/thread: rows rg*4+k, col jl)
    float cc[4], oo[4], sv[4], qv[4];
    #pragma unroll
    for (int k = 0; k < 4; ++k) {
      const int row = rg * 4 + k;
      const float gi = gates[(0 * 64 + row) * 17 + jl] + bi;
      const float gf = gates[(1 * 64 + row) * 17 + jl] + bf_;
      const float go = gates[(2 * 64 + row) * 17 + jl] + bo;
      const float gc = gates[(3 * 64 + row) * 17 + jl] + bc;
      const float iv = 1.f / (1.f + __expf(-gi));
      const float fv = 1.f / (1.f + __expf(-gf));
      oo[k] = 1.f / (1.f + __expf(-go));
      const float cn = iv * tanhf(gc) + fv * cst[k];
      cst[k] = cn; cc[k] = cn;
      sv[k] = cn; qv[k] = cn * cn;
    }
    #pragma unroll
    for (int m = 1; m <= 8; m <<= 1)
      #pragma unroll
      for (int k = 0; k < 4; ++k) { sv[k] += __shfl_xor(sv[k], m); qv[k] += __shfl_xor(qv[k], m); }
    if (jl == 0) {
      #pragma unroll
      for (int k = 0; k < 4; ++k) {
        const int row = rg * 4 + k;
        const float qs = (t & 1) ? -qv[k] : qv[k];      // parity in signbit
        stg8_coh(statT + ((size_t)row * 32 + ns) * 2, sv[k], qs);
      }
    }

    // ------------- stats poll: wave w polls exactly rows 16w..16w+15
    {
      const float* base = statT + (((size_t)(tid >> 2) * 32) + (size_t)(tid & 3) * 8) * 2;
      const u32 want = (u32)(t & 1);
      f32x2 e[8];
      while (true) {
        #pragma unroll
        for (int j = 0; j < 8; ++j) ldg8f_coh(e[j], base + j * 2);
        vm_wait();
        bool ok = true;
        #pragma unroll
        for (int j = 0; j < 8; ++j) ok &= ((__float_as_uint(e[j][1]) >> 31) == want);
        if (__all((int)ok)) break;
        __builtin_amdgcn_s_sleep(1);
      }
      float ss = 0.f, qq = 0.f;
      #pragma unroll
      for (int j = 0; j < 8; ++j) { ss += e[j][0]; qq += __builtin_fabsf(e[j][1]); }
      ss += __shfl_xor(ss, 1); qq += __shfl_xor(qq, 1);
      ss += __shfl_xor(ss, 2); qq += __shfl_xor(qq, 2);
      if ((lane & 3) == 0) {
        const int row = tid >> 2;
        const float mu = ss * (1.f / 512.f);
        const float ms = qq * (1.f / 512.f);
        mus[row * 2] = mu;
        mus[row * 2 + 1] = rsqrtf(ms - mu * mu + 1e-5f);
      }
    }
    // wave-local mus (same wave wrote the rows it reads) — no barrier needed

    // ------------- h + stores
    #pragma unroll
    for (int k = 0; k < 4; ++k) {
      const int row = rg * 4 + k;
      const float mu = mus[row * 2], rs = mus[row * 2 + 1];
      const float hv = oo[k] * tanhf((cc[k] - mu) * rs * gm + bt);
      const u32 h16 = f2bf(hv);
      if (ROLE == 0) {
        stg2_coh(hA + (size_t)(t & 1) * 32768 + (size_t)row * 512 + jg, h16);
      } else {
        stg2_coh(hB + (size_t)(t & 1) * 32768 + (size_t)row * 512 + jg, h16);
        out[((size_t)t * 64 + row) * 512 + jg] = hv;
      }
      if (t == kSeq - 1) {
        out[OUT_HFIN + (size_t)ROLE * 32768 + (size_t)row * 512 + jg] = hv;
        out[OUT_CFIN + (size_t)ROLE * 32768 + (size_t)row * 512 + jg] = cc[k];
      }
    }
    vm_wait();
    __syncthreads();
    if (tid == 0)
      __hip_atomic_store(&HF[ns], (u32)(t + 1), __ATOMIC_RELAXED, __HIP_MEMORY_SCOPE_AGENT);
  }
}

// ---------------------------------------------------------------- persistent
__global__ __launch_bounds__(256, 1) void lstm_persist(
    const u16* __restrict__ xbf, const u16* __restrict__ w0s, const u16* __restrict__ w1s,
    char* ws,
    const float* __restrict__ b0, const float* __restrict__ lg0, const float* __restrict__ lb0,
    const float* __restrict__ b1, const float* __restrict__ lg1, const float* __restrict__ lb1,
    const float* __restrict__ c0in, float* __restrict__ out)
{
  extern __shared__ char smem[];
  const int bid = blockIdx.x;
  u32*   flags = (u32*)(ws + OF_FLAGS);
  u16*   hA    = (u16*)(ws + OF_HA);
  u16*   hB    = (u16*)(ws + OF_HB);
  float* st0   = (float*)(ws + OF_STAT0);
  float* st1   = (float*)(ws + OF_STAT1);

  if (bid < 32)
    team_loop<0>(bid, smem, xbf, w0s, hA, hB, st0, flags, b0, lg0, lb0, c0in, out);
  else
    team_loop<1>(bid - 32, smem, xbf, w1s, hA, hB, st1, flags, b1, lg1, lb1, c0in, out);
}

// ---------------------------------------------------------------- launch
extern "C" void kernel_launch(void* const* d_in, const int* in_sizes, int n_in,
                              void* d_out, int out_size, void* d_ws, size_t ws_size,
                              hipStream_t stream) {
  (void)in_sizes; (void)n_in; (void)out_size;
  const float* x   = (const float*)d_in[0];
  const float* h0  = (const float*)d_in[1];
  const float* c0  = (const float*)d_in[2];
  const float* W0  = (const float*)d_in[3];
  const float* b0  = (const float*)d_in[4];
  const float* g0  = (const float*)d_in[5];
  const float* be0 = (const float*)d_in[6];
  const float* W1  = (const float*)d_in[7];
  const float* b1  = (const float*)d_in[8];
  const float* g1  = (const float*)d_in[9];
  const float* be1 = (const float*)d_in[10];
  float* out = (float*)d_out;

  if (ws_size < WS_NEED) return;   // fail loudly (output stays poisoned)

  char* ws = (char*)d_ws;
  u16* w0s = (u16*)(ws + OF_W0S);
  u16* w1s = (u16*)(ws + OF_W1S);
  u16* xbf = (u16*)(ws + OF_XBF);

  hipLaunchKernelGGL(conv_x_k, dim3(2048), dim3(256), 0, stream,
                     x, xbf, (size_t)kSeq * 64 * 256);
  hipLaunchKernelGGL(conv_w_k, dim3(6144), dim3(256), 0, stream, W0, w0s, 24, 768);
  hipLaunchKernelGGL(conv_w_k, dim3(8192), dim3(256), 0, stream, W1, w1s, 32, 1024);
  hipLaunchKernelGGL(init_k,   dim3(128),  dim3(256), 0, stream, ws, h0);
  hipLaunchKernelGGL(lstm_persist, dim3(64), dim3(256), 148992, stream,
                     xbf, w0s, w1s, ws,
                     b0, g0, be0, b1, g1, be1, c0, out);
}